// Round 6
// baseline (103.491 us; speedup 1.0000x reference)
//
#include <hip/hip_runtime.h>
#include <hip/hip_bf16.h>

#define NN 32
#define LL 4096
#define EE 512
#define HH 8
#define DD 64
#define FF 2048
#define CC 8            // row chunks per head-block (512 rows / 64)

typedef float f32x4 __attribute__((ext_vector_type(4)));

// ---------------------------------------------------------------------------
// K1 (R2-proven shape): blocks 0..2047: P[c][n][h][e] = 64-row partial sums
// of Cp; blocks 2048..2079: V[d][e] = sum_{j<8} W1[j*64+d][e]
__global__ void k_prep(const float* __restrict__ Cp, const float* __restrict__ W1,
                       float* __restrict__ P, float* __restrict__ V) {
    int bid = blockIdx.x;
    int tid = threadIdx.x;                 // 0..127
    if (bid < 2048) {
        int c = bid & 7;
        int h = (bid >> 3) & 7;
        int n = bid >> 6;
        const float4* base = reinterpret_cast<const float4*>(
            Cp + ((size_t)n * LL + (size_t)h * 512 + (size_t)c * 64) * EE) + tid;
        float ax = 0.f, ay = 0.f, az = 0.f, aw = 0.f;
#pragma unroll 8
        for (int r = 0; r < 64; ++r) {
            float4 v = base[(size_t)r * (EE / 4)];
            ax += v.x; ay += v.y; az += v.z; aw += v.w;
        }
        float4 o; o.x = ax; o.y = ay; o.z = az; o.w = aw;
        reinterpret_cast<float4*>(P + (((size_t)c * NN + n) * HH + h) * EE)[tid] = o;
    } else {
        int gid2 = (bid - 2048) * 128 + tid;     // 0..4095, 2 float4 outputs each
#pragma unroll
        for (int rep = 0; rep < 2; ++rep) {
            int idx = gid2 + rep * 4096;         // 0..8191
            int d = idx >> 7;
            int e4 = idx & 127;
            float ax = 0.f, ay = 0.f, az = 0.f, aw = 0.f;
#pragma unroll
            for (int j = 0; j < 8; ++j) {
                float4 v = reinterpret_cast<const float4*>(
                    W1 + (size_t)(j * 64 + d) * EE)[e4];
                ax += v.x; ay += v.y; az += v.z; aw += v.w;
            }
            float4 o; o.x = ax; o.y = ay; o.z = az; o.w = aw;
            reinterpret_cast<float4*>(V + (size_t)d * EE)[e4] = o;
        }
    }
}

// ---------------------------------------------------------------------------
// K2: fused phi + w3.  128 blocks = (n, j), j = quarter of the 512 w3 outputs.
//   stage 1: S[h][e] = sum_c P[c][n][h][e]          (16 KB LDS)
//   stage 2: ph[h*64+d] = sum_e S[h][e] * V[d][e]   (2 KB LDS)
//   stage 3: w3[n][j*128 + i] = sum_k ph[k] * W3[j*128+i][k]
__global__ __launch_bounds__(256) void k_phiw3(const float* __restrict__ P,
                                               const float* __restrict__ V,
                                               const float* __restrict__ W3,
                                               float* __restrict__ w3) {
    __shared__ float S[HH * EE];      // 16 KB
    __shared__ float ph[EE];          // 2 KB
    __shared__ float red[256];
    int n = blockIdx.x >> 2;
    int j = blockIdx.x & 3;
    int t = threadIdx.x;

    f32x4* S4 = reinterpret_cast<f32x4*>(S);
    const f32x4* P4 = reinterpret_cast<const f32x4*>(P);
#pragma unroll
    for (int cc = 0; cc < 4; ++cc) {
        int idx = cc * 256 + t;       // 0..1023 float4 covering (h,e) for this n
        f32x4 a = P4[(size_t)(0 * NN + n) * 1024 + idx];
#pragma unroll
        for (int c = 1; c < CC; ++c) {
            f32x4 b = P4[(size_t)(c * NN + n) * 1024 + idx];
            a.x += b.x; a.y += b.y; a.z += b.z; a.w += b.w;
        }
        S4[idx] = a;
    }
    __syncthreads();

#pragma unroll
    for (int rep = 0; rep < 2; ++rep) {
        int o = t + rep * 256;
        int h = o >> 6, d = o & 63;
        const f32x4* Vr = reinterpret_cast<const f32x4*>(V) + (size_t)d * 128;
        const f32x4* Sr = reinterpret_cast<const f32x4*>(S) + (size_t)h * 128;
        float acc = 0.f;
#pragma unroll 4
        for (int k = 0; k < 128; ++k) {
            f32x4 s = Sr[k], v = Vr[k];
            acc += s.x * v.x + s.y * v.y + s.z * v.z + s.w * v.w;
        }
        ph[o] = acc;
    }
    __syncthreads();

    int f  = j * 128 + (t >> 1);
    int eh = t & 1;
    const f32x4* Wr = reinterpret_cast<const f32x4*>(W3) + (size_t)f * 128 + eh * 64;
    const f32x4* Pr = reinterpret_cast<const f32x4*>(ph) + eh * 64;
    float acc = 0.f;
#pragma unroll 4
    for (int k = 0; k < 64; ++k) {
        f32x4 p = Pr[k], w = Wr[k];
        acc += p.x * w.x + p.y * w.y + p.z * w.z + p.w * w.w;
    }
    red[t] = acc;
    __syncthreads();
    if (t < 128) w3[(size_t)n * EE + j * 128 + t] = red[2 * t] + red[2 * t + 1];
}

// ---------------------------------------------------------------------------
// Skinny GEMM (R2-proven): out[n][f] = act( A[n][:K] . W[f][:K] (+bias)(+res) )
// MODE: 0 = plain, 1 = relu(s + bias), 2 = s + bias + res
template<int K, int F, int NG, int FPW, int MODE>
__global__ __launch_bounds__(256) void k_gemm(const float* __restrict__ A,
                                              const float* __restrict__ W,
                                              const float* __restrict__ bias,
                                              const float* __restrict__ res,
                                              float* __restrict__ out) {
    constexpr int V4 = K / 256;
    int wid  = (blockIdx.x * 256 + threadIdx.x) >> 6;
    int lane = threadIdx.x & 63;
    constexpr int NGROUPS = NN / NG;
    int ng = wid % NGROUPS;
    int fc = wid / NGROUPS;
    int n0 = ng * NG;
    int f0 = fc * FPW;

    float4 a4[NG][V4];
#pragma unroll
    for (int g = 0; g < NG; ++g)
#pragma unroll
        for (int k = 0; k < V4; ++k)
            a4[g][k] = reinterpret_cast<const float4*>(
                A + (size_t)(n0 + g) * K)[k * 64 + lane];

#pragma unroll
    for (int fi = 0; fi < FPW; ++fi) {
        int f = f0 + fi;
        float4 w4[V4];
#pragma unroll
        for (int k = 0; k < V4; ++k)
            w4[k] = reinterpret_cast<const float4*>(
                W + (size_t)f * K)[k * 64 + lane];
        float acc[NG];
#pragma unroll
        for (int g = 0; g < NG; ++g) {
            float s = 0.f;
#pragma unroll
            for (int k = 0; k < V4; ++k) {
                s += a4[g][k].x * w4[k].x + a4[g][k].y * w4[k].y
                   + a4[g][k].z * w4[k].z + a4[g][k].w * w4[k].w;
            }
#pragma unroll
            for (int m = 32; m > 0; m >>= 1) s += __shfl_xor(s, m);
            acc[g] = s;
        }
        if (lane == 0) {
            float b = (MODE == 0) ? 0.f : bias[f];
#pragma unroll
            for (int g = 0; g < NG; ++g) {
                float v = acc[g] + b;
                if (MODE == 1) v = fmaxf(v, 0.f);
                if (MODE == 2) v += res[(size_t)(n0 + g) * F + f];
                out[(size_t)(n0 + g) * F + f] = v;
            }
        }
    }
}

// ---------------------------------------------------------------------------
// K5: LayerNorm (R2-proven)
__global__ void k_ln(const float* __restrict__ x, const float* __restrict__ gamma,
                     const float* __restrict__ beta, float* __restrict__ out) {
    __shared__ float wred[4];
    int n = blockIdx.x;
    int tid = threadIdx.x;
    float a = x[(size_t)n * EE + tid];
    float b = x[(size_t)n * EE + 256 + tid];
    float s = a + b;
#pragma unroll
    for (int off = 32; off > 0; off >>= 1) s += __shfl_down(s, off);
    int wid = tid >> 6;
    if ((tid & 63) == 0) wred[wid] = s;
    __syncthreads();
    if (tid == 0) wred[0] = (wred[0] + wred[1] + wred[2] + wred[3]) * (1.0f / EE);
    __syncthreads();
    float mu = wred[0];
    float da = a - mu, db = b - mu;
    float q = da * da + db * db;
#pragma unroll
    for (int off = 32; off > 0; off >>= 1) q += __shfl_down(q, off);
    __syncthreads();
    if ((tid & 63) == 0) wred[wid] = q;
    __syncthreads();
    if (tid == 0) wred[0] = (wred[0] + wred[1] + wred[2] + wred[3]) * (1.0f / EE);
    __syncthreads();
    float var = wred[0];
    float rstd = rsqrtf(var + 1e-5f);
    out[(size_t)n * EE + tid]       = da * rstd * gamma[tid] + beta[tid];
    out[(size_t)n * EE + 256 + tid] = db * rstd * gamma[tid + 256] + beta[tid + 256];
}

// ---------------------------------------------------------------------------
extern "C" void kernel_launch(void* const* d_in, const int* in_sizes, int n_in,
                              void* d_out, int out_size, void* d_ws, size_t ws_size,
                              hipStream_t stream) {
    const float* Cp    = (const float*)d_in[0];
    const float* W1    = (const float*)d_in[1];
    // d_in[2] = W2: unused — softmax over a size-1 axis is identically 1.
    const float* W3    = (const float*)d_in[3];
    const float* Wf1   = (const float*)d_in[4];
    const float* bf1   = (const float*)d_in[5];
    const float* Wf2   = (const float*)d_in[6];
    const float* bf2   = (const float*)d_in[7];
    const float* gamma = (const float*)d_in[8];
    const float* beta  = (const float*)d_in[9];
    float* out = (float*)d_out;
    float* ws  = (float*)d_ws;

    float* P  = ws;                               // 8*32*8*512 = 1,048,576 floats
    float* V  = P + (size_t)CC * NN * HH * EE;    // 64*512
    float* w3 = V + (size_t)DD * EE;              // 32*512
    float* h1 = w3 + (size_t)NN * EE;             // 32*2048
    float* x  = h1 + (size_t)NN * FF;             // 32*512

    // K1: Cp row-block partial sums + W1 colsums (R2-proven config)
    k_prep<<<2048 + 32, 128, 0, stream>>>(Cp, W1, P, V);
    // K2: fused phi + w3
    k_phiw3<<<NN * 4, 256, 0, stream>>>(P, V, W3, w3);
    // K3: h1 = relu(w3 @ Wf1^T + bf1)
    k_gemm<EE, FF, 8, 2, 1><<<1024, 256, 0, stream>>>(w3, Wf1, bf1, nullptr, h1);
    // K4: x = h1 @ Wf2^T + bf2 + w3
    k_gemm<FF, EE, 4, 1, 2><<<1024, 256, 0, stream>>>(h1, Wf2, bf2, w3, x);
    // K5: LayerNorm
    k_ln<<<NN, 256, 0, stream>>>(x, gamma, beta, out);
}

// Round 7
// 78.344 us; speedup vs baseline: 1.3210x; 1.3210x over previous
//
#include <hip/hip_runtime.h>
#include <hip/hip_bf16.h>

#define NN 32
#define LL 4096
#define EE 512
#define HH 8
#define DD 64
#define FF 2048
#define CC 8            // row chunks per head-block (512 rows / 64)

typedef float f32x4 __attribute__((ext_vector_type(4)));

// ---------------------------------------------------------------------------
// K1 (R2-proven): blocks 0..2047: P[c][n][h][e] = 64-row partial sums of Cp;
// blocks 2048..2079: V[d][e] = sum_{j<8} W1[j*64+d][e]
__global__ void k_prep(const float* __restrict__ Cp, const float* __restrict__ W1,
                       float* __restrict__ P, float* __restrict__ V) {
    int bid = blockIdx.x;
    int tid = threadIdx.x;                 // 0..127
    if (bid < 2048) {
        int c = bid & 7;
        int h = (bid >> 3) & 7;
        int n = bid >> 6;
        const float4* base = reinterpret_cast<const float4*>(
            Cp + ((size_t)n * LL + (size_t)h * 512 + (size_t)c * 64) * EE) + tid;
        float ax = 0.f, ay = 0.f, az = 0.f, aw = 0.f;
#pragma unroll 8
        for (int r = 0; r < 64; ++r) {
            float4 v = base[(size_t)r * (EE / 4)];
            ax += v.x; ay += v.y; az += v.z; aw += v.w;
        }
        float4 o; o.x = ax; o.y = ay; o.z = az; o.w = aw;
        reinterpret_cast<float4*>(P + (((size_t)c * NN + n) * HH + h) * EE)[tid] = o;
    } else {
        int gid2 = (bid - 2048) * 128 + tid;     // 0..4095, 2 float4 outputs each
#pragma unroll
        for (int rep = 0; rep < 2; ++rep) {
            int idx = gid2 + rep * 4096;         // 0..8191
            int d = idx >> 7;
            int e4 = idx & 127;
            float ax = 0.f, ay = 0.f, az = 0.f, aw = 0.f;
#pragma unroll
            for (int j = 0; j < 8; ++j) {
                float4 v = reinterpret_cast<const float4*>(
                    W1 + (size_t)(j * 64 + d) * EE)[e4];
                ax += v.x; ay += v.y; az += v.z; aw += v.w;
            }
            float4 o; o.x = ax; o.y = ay; o.z = az; o.w = aw;
            reinterpret_cast<float4*>(V + (size_t)d * EE)[e4] = o;
        }
    }
}

// ---------------------------------------------------------------------------
// K2: phi, coalesced-V version.  256 blocks = (n,h), 256 threads = 4 waves.
//   stage 1: S[e] = sum_c P[c][n][h][e]                (coalesced, LDS 2 KB)
//   stage 2: wave w handles d = w*16..w*16+15; for each d the 64 lanes read
//            V[d][:] as 2 coalesced f32x4, dot with LDS S, shfl_xor reduce.
__global__ __launch_bounds__(256) void k_phi(const float* __restrict__ P,
                                             const float* __restrict__ V,
                                             float* __restrict__ phi) {
    __shared__ float S[EE];
    int n = blockIdx.x >> 3;
    int h = blockIdx.x & 7;
    int t = threadIdx.x;

#pragma unroll
    for (int rep = 0; rep < 2; ++rep) {
        int e = t + rep * 256;
        float s = 0.f;
#pragma unroll
        for (int c = 0; c < CC; ++c)
            s += P[(((size_t)c * NN + n) * HH + h) * EE + e];
        S[e] = s;
    }
    __syncthreads();

    int w    = t >> 6;                 // wave 0..3
    int lane = t & 63;
    const f32x4* S4 = reinterpret_cast<const f32x4*>(S);
    f32x4 s0 = S4[lane];
    f32x4 s1 = S4[64 + lane];
#pragma unroll
    for (int i = 0; i < 16; ++i) {
        int d = w * 16 + i;
        const f32x4* Vr = reinterpret_cast<const f32x4*>(V) + (size_t)d * 128;
        f32x4 v0 = Vr[lane];
        f32x4 v1 = Vr[64 + lane];
        float acc = s0.x * v0.x + s0.y * v0.y + s0.z * v0.z + s0.w * v0.w
                  + s1.x * v1.x + s1.y * v1.y + s1.z * v1.z + s1.w * v1.w;
#pragma unroll
        for (int m = 32; m > 0; m >>= 1) acc += __shfl_xor(acc, m);
        if (lane == 0) phi[(size_t)n * EE + h * DD + d] = acc;
    }
}

// ---------------------------------------------------------------------------
// Skinny GEMM (R2-proven): out[n][f] = act( A[n][:K] . W[f][:K] (+bias)(+res) )
// MODE: 0 = plain, 1 = relu(s + bias), 2 = s + bias + res
template<int K, int F, int NG, int FPW, int MODE>
__global__ __launch_bounds__(256) void k_gemm(const float* __restrict__ A,
                                              const float* __restrict__ W,
                                              const float* __restrict__ bias,
                                              const float* __restrict__ res,
                                              float* __restrict__ out) {
    constexpr int V4 = K / 256;
    int wid  = (blockIdx.x * 256 + threadIdx.x) >> 6;
    int lane = threadIdx.x & 63;
    constexpr int NGROUPS = NN / NG;
    int ng = wid % NGROUPS;
    int fc = wid / NGROUPS;
    int n0 = ng * NG;
    int f0 = fc * FPW;

    float4 a4[NG][V4];
#pragma unroll
    for (int g = 0; g < NG; ++g)
#pragma unroll
        for (int k = 0; k < V4; ++k)
            a4[g][k] = reinterpret_cast<const float4*>(
                A + (size_t)(n0 + g) * K)[k * 64 + lane];

#pragma unroll
    for (int fi = 0; fi < FPW; ++fi) {
        int f = f0 + fi;
        float4 w4[V4];
#pragma unroll
        for (int k = 0; k < V4; ++k)
            w4[k] = reinterpret_cast<const float4*>(
                W + (size_t)f * K)[k * 64 + lane];
        float acc[NG];
#pragma unroll
        for (int g = 0; g < NG; ++g) {
            float s = 0.f;
#pragma unroll
            for (int k = 0; k < V4; ++k) {
                s += a4[g][k].x * w4[k].x + a4[g][k].y * w4[k].y
                   + a4[g][k].z * w4[k].z + a4[g][k].w * w4[k].w;
            }
#pragma unroll
            for (int m = 32; m > 0; m >>= 1) s += __shfl_xor(s, m);
            acc[g] = s;
        }
        if (lane == 0) {
            float b = (MODE == 0) ? 0.f : bias[f];
#pragma unroll
            for (int g = 0; g < NG; ++g) {
                float v = acc[g] + b;
                if (MODE == 1) v = fmaxf(v, 0.f);
                if (MODE == 2) v += res[(size_t)(n0 + g) * F + f];
                out[(size_t)(n0 + g) * F + f] = v;
            }
        }
    }
}

// ---------------------------------------------------------------------------
// K6: LayerNorm (R2-proven)
__global__ void k_ln(const float* __restrict__ x, const float* __restrict__ gamma,
                     const float* __restrict__ beta, float* __restrict__ out) {
    __shared__ float wred[4];
    int n = blockIdx.x;
    int tid = threadIdx.x;
    float a = x[(size_t)n * EE + tid];
    float b = x[(size_t)n * EE + 256 + tid];
    float s = a + b;
#pragma unroll
    for (int off = 32; off > 0; off >>= 1) s += __shfl_down(s, off);
    int wid = tid >> 6;
    if ((tid & 63) == 0) wred[wid] = s;
    __syncthreads();
    if (tid == 0) wred[0] = (wred[0] + wred[1] + wred[2] + wred[3]) * (1.0f / EE);
    __syncthreads();
    float mu = wred[0];
    float da = a - mu, db = b - mu;
    float q = da * da + db * db;
#pragma unroll
    for (int off = 32; off > 0; off >>= 1) q += __shfl_down(q, off);
    __syncthreads();
    if ((tid & 63) == 0) wred[wid] = q;
    __syncthreads();
    if (tid == 0) wred[0] = (wred[0] + wred[1] + wred[2] + wred[3]) * (1.0f / EE);
    __syncthreads();
    float var = wred[0];
    float rstd = rsqrtf(var + 1e-5f);
    out[(size_t)n * EE + tid]       = da * rstd * gamma[tid] + beta[tid];
    out[(size_t)n * EE + 256 + tid] = db * rstd * gamma[tid + 256] + beta[tid + 256];
}

// ---------------------------------------------------------------------------
extern "C" void kernel_launch(void* const* d_in, const int* in_sizes, int n_in,
                              void* d_out, int out_size, void* d_ws, size_t ws_size,
                              hipStream_t stream) {
    const float* Cp    = (const float*)d_in[0];
    const float* W1    = (const float*)d_in[1];
    // d_in[2] = W2: unused — softmax over a size-1 axis is identically 1.
    const float* W3    = (const float*)d_in[3];
    const float* Wf1   = (const float*)d_in[4];
    const float* bf1   = (const float*)d_in[5];
    const float* Wf2   = (const float*)d_in[6];
    const float* bf2   = (const float*)d_in[7];
    const float* gamma = (const float*)d_in[8];
    const float* beta  = (const float*)d_in[9];
    float* out = (float*)d_out;
    float* ws  = (float*)d_ws;

    float* P   = ws;                              // 8*32*8*512 = 1,048,576 floats
    float* V   = P + (size_t)CC * NN * HH * EE;   // 64*512
    float* phi = V + (size_t)DD * EE;             // 32*512
    float* w3  = phi + (size_t)NN * EE;           // 32*512
    float* h1  = w3 + (size_t)NN * EE;            // 32*2048
    float* x   = h1 + (size_t)NN * FF;            // 32*512

    // K1: Cp row-block partial sums + W1 colsums (R2-proven config)
    k_prep<<<2048 + 32, 128, 0, stream>>>(Cp, W1, P, V);
    // K2: phi (coalesced-V wave-per-output)
    k_phi<<<NN * HH, 256, 0, stream>>>(P, V, phi);
    // K3: w3 = phi @ W3^T
    k_gemm<EE, EE, 8, 2, 0><<<256, 256, 0, stream>>>(phi, W3, nullptr, nullptr, w3);
    // K4: h1 = relu(w3 @ Wf1^T + bf1)
    k_gemm<EE, FF, 8, 2, 1><<<1024, 256, 0, stream>>>(w3, Wf1, bf1, nullptr, h1);
    // K5: x = h1 @ Wf2^T + bf2 + w3
    k_gemm<FF, EE, 4, 1, 2><<<1024, 256, 0, stream>>>(h1, Wf2, bf2, w3, x);
    // K6: LayerNorm
    k_ln<<<NN, 256, 0, stream>>>(x, gamma, beta, out);
}